// Round 7
// baseline (1932.714 us; speedup 1.0000x reference)
//
#include <hip/hip_runtime.h>

typedef unsigned short u16;
typedef unsigned int u32;
typedef __attribute__((ext_vector_type(8))) short bf16x8;
typedef __attribute__((ext_vector_type(4))) float f32x4;
typedef __attribute__((ext_vector_type(2))) unsigned int u32x2;

#define MFMA_BF16(a,b,c) __builtin_amdgcn_mfma_f32_16x16x32_bf16((a),(b),(c),0,0,0)

__device__ __forceinline__ u16 f2bf(float f) {
  union { float f; u32 u; } v; v.f = f;
  u32 r = v.u + 0x7FFFu + ((v.u >> 16) & 1u);
  return (u16)(r >> 16);
}
__device__ __forceinline__ float bf2f(u16 h) {
  union { u32 u; float f; } v; v.u = ((u32)h) << 16; return v.f;
}
__device__ __forceinline__ float tanh_fast(float x) {
  float e = __expf(2.0f * x);
  return 1.0f - 2.0f / (e + 1.0f);
}
__device__ __forceinline__ float exp2_fast(float x) {
  float r; asm("v_exp_f32 %0, %1" : "=v"(r) : "v"(x)); return r;
}
__device__ __forceinline__ float rcp_fast(float x) {
  float r; asm("v_rcp_f32 %0, %1" : "=v"(r) : "v"(x)); return r;
}

// ---- coherent (cross-XCD) ld/st ------------------------------------------
__device__ __forceinline__ void issue_lcoh(bf16x8& v, const u16* p) {
  asm volatile("global_load_dwordx4 %0, %1, off sc0 sc1" : "=v"(v) : "v"(p));
}
__device__ __forceinline__ void vm_wait0() {
  asm volatile("s_waitcnt vmcnt(0)" ::: "memory");
  __builtin_amdgcn_sched_barrier(0);
}
__device__ __forceinline__ void scoh_u32(u32* p, u32 v) {
  asm volatile("global_store_dword %0, %1, off sc0 sc1" :: "v"(p), "v"(v) : "memory");
}
__device__ __forceinline__ void scoh_dx2(u16* p, u32 lo, u32 hi) {
  u32x2 v; v.x = lo; v.y = hi;
  asm volatile("global_store_dwordx2 %0, %1, off sc0 sc1" :: "v"(p), "v"(v) : "memory");
}
__device__ __forceinline__ void scoh_dx4(u16* p, bf16x8 v) {
  asm volatile("global_store_dwordx4 %0, %1, off sc0 sc1" :: "v"(p), "v"(v) : "memory");
}
__device__ __forceinline__ u32 poll_load(const u32* p) {
  u32 v;
  asm volatile("global_load_dword %0, %1, off sc0 sc1\n\ts_waitcnt vmcnt(0)"
               : "=v"(v) : "v"(p) : "memory");
  return v;
}

// Poll P per-producer flag slots (128B apart) until all >= target.
__device__ __forceinline__ void poll_flags(const u32* base, int P, u32 target) {
  if (target == 0u) return;
  if ((threadIdx.x >> 6) == 0) {
    const int lane = threadIdx.x & 63;
    const u32* s0 = base + (size_t)(lane & (P - 1)) * 32;
    for (;;) {
      u32 v0 = poll_load(s0);
      if (__all(v0 >= target)) break;
      __builtin_amdgcn_s_sleep(1);
    }
  }
  __syncthreads();
  __builtin_amdgcn_sched_barrier(0);
}
__device__ __forceinline__ void post_flag(u32* slot, u32 val) {
  asm volatile("s_waitcnt vmcnt(0)" ::: "memory");
  __syncthreads();
  if (threadIdx.x == 0) scoh_u32(slot, val);
}

// ---------------------------------------------------------------------------
// Prep
// ---------------------------------------------------------------------------
__global__ void prep_kernel(
    const float* __restrict__ fcw, const float* __restrict__ enc,
    const float* __restrict__ wenc, const float* __restrict__ wdec,
    const float* __restrict__ wih0, const float* __restrict__ whh0,
    const float* __restrict__ wih1, const float* __restrict__ whh1,
    const float* __restrict__ bih0, const float* __restrict__ bhh0,
    const float* __restrict__ bih1, const float* __restrict__ bhh1,
    const float* __restrict__ emb, const int* __restrict__ yin,
    const float* __restrict__ dih,
    u16* __restrict__ fcwb, u16* __restrict__ encb, u16* __restrict__ wencb,
    u16* __restrict__ wdecb, u16* __restrict__ w0eh, u16* __restrict__ w0ctx,
    u16* __restrict__ w1cat, u16* __restrict__ embbt,
    float* __restrict__ bias0, float* __restrict__ bias1,
    u16* __restrict__ h0buf0, u16* __restrict__ h1buf0)
{
  const float SCL = 2.8853900817779268f;   // 2*log2(e)
  const long long total = 43845632LL;
  for (long long i = (long long)blockIdx.x * 256 + threadIdx.x; i < total;
       i += (long long)gridDim.x * 256) {
    if (i < 32768000LL) {
      int r = (int)(i >> 10), c = (int)(i & 1023);
      fcwb[i] = (r < 31999) ? f2bf(fcw[(long long)r * 1024 + c]) : (u16)0;
    } else if (i < 36962304LL) {
      long long j = i - 32768000LL; encb[j] = f2bf(enc[j]);
    } else if (i < 37486592LL) {
      long long j = i - 36962304LL; wencb[j] = f2bf(wenc[j] * SCL);
    } else if (i < 38010880LL) {
      long long j = i - 37486592LL; wdecb[j] = f2bf(wdec[j] * SCL);
    } else if (i < 39583744LL) {             // w0eh [1024][1536]: [Wih0_emb|Whh0]
      long long j = i - 38010880LL;
      int r = (int)(j / 1536), c = (int)(j % 1536);
      float v = (c < 512) ? wih0[(long long)r * 1536 + c]
                          : whh0[(long long)r * 1024 + (c - 512)];
      w0eh[j] = f2bf(v);
    } else if (i < 40632320LL) {             // w0ctx [1024][1024] = Wih0[:,512:1536]
      long long j = i - 39583744LL;
      int r = (int)(j >> 10), e = (int)(j & 1023);
      w0ctx[j] = f2bf(wih0[(long long)r * 1536 + 512 + e]);
    } else if (i < 42729472LL) {             // w1cat [1024][2048]: [Wih1|Whh1]
      long long j = i - 40632320LL;
      int r = (int)(j >> 11), c = (int)(j & 2047);
      w1cat[j] = f2bf(c < 1024 ? wih1[(r << 10) + c] : whh1[(r << 10) + (c - 1024)]);
    } else if (i < 43778048LL) {             // embedding gather
      long long j = i - 42729472LL;
      int bt = (int)(j >> 9), c = (int)(j & 511);
      int y = yin[bt];
      embbt[j] = f2bf(emb[(long long)y * 512 + c]);
    } else if (i < 43779072LL) {
      int j = (int)(i - 43778048LL); bias0[j] = bih0[j] + bhh0[j];
    } else if (i < 43780096LL) {
      int j = (int)(i - 43779072LL); bias1[j] = bih1[j] + bhh1[j];
    } else if (i < 43812864LL) {
      int j = (int)(i - 43780096LL); h0buf0[j] = f2bf(dih[j]);
    } else {
      int j = (int)(i - 43812864LL); h1buf0[j] = f2bf(dih[32768 + j]);
    }
  }
}

// ---------------------------------------------------------------------------
// Generic 128x128-tile bf16 MFMA GEMM
// ---------------------------------------------------------------------------
template <int OUT16>
__global__ __launch_bounds__(256) void gemm128(
    const u16* __restrict__ A, const u16* __restrict__ Bm,
    const float* __restrict__ bias, void* __restrict__ Cv,
    int K, int ldc, int Nvalid, int ntN)
{
  __shared__ u16 As[128 * 32];
  __shared__ u16 Bs[128 * 32];
  const int tid = threadIdx.x;
  const int bid = blockIdx.x;
  const int tM = bid / ntN, tN = bid - tM * ntN;
  const int m0 = tM * 128, n0 = tN * 128;
  const int lane = tid & 63, wid = tid >> 6;
  const int wm = wid >> 1, wn = wid & 1;
  const int srow = tid >> 1, scol = (tid & 1) * 16;

  const u16* gA = A + (size_t)(m0 + srow) * K + scol;
  const u16* gB = Bm + (size_t)(n0 + srow) * K + scol;
  u16* sA = &As[srow * 32 + scol];
  u16* sB = &Bs[srow * 32 + scol];

  f32x4 acc[4][4];
#pragma unroll
  for (int i = 0; i < 4; ++i)
#pragma unroll
    for (int j = 0; j < 4; ++j) acc[i][j] = (f32x4){0, 0, 0, 0};

  const int aoff = (wm * 64 + (lane & 15)) * 32 + ((lane >> 4) << 3);
  const int boff = (wn * 64 + (lane & 15)) * 32 + ((lane >> 4) << 3);

  for (int k0 = 0; k0 < K; k0 += 32) {
    bf16x8 va0 = *(const bf16x8*)(gA + k0);
    bf16x8 va1 = *(const bf16x8*)(gA + k0 + 8);
    bf16x8 vb0 = *(const bf16x8*)(gB + k0);
    bf16x8 vb1 = *(const bf16x8*)(gB + k0 + 8);
    __syncthreads();
    *((bf16x8*)sA) = va0;  *((bf16x8*)(sA + 8)) = va1;
    *((bf16x8*)sB) = vb0;  *((bf16x8*)(sB + 8)) = vb1;
    __syncthreads();
    bf16x8 af[4], bfj[4];
#pragma unroll
    for (int i = 0; i < 4; ++i) af[i] = *(const bf16x8*)&As[aoff + i * 512];
#pragma unroll
    for (int j = 0; j < 4; ++j) bfj[j] = *(const bf16x8*)&Bs[boff + j * 512];
#pragma unroll
    for (int i = 0; i < 4; ++i)
#pragma unroll
      for (int j = 0; j < 4; ++j)
        acc[i][j] = MFMA_BF16(af[i], bfj[j], acc[i][j]);
  }

#pragma unroll
  for (int i = 0; i < 4; ++i) {
#pragma unroll
    for (int j = 0; j < 4; ++j) {
      int row = m0 + wm * 64 + i * 16 + ((lane >> 4) << 2);
      int cc = n0 + wn * 64 + j * 16 + (lane & 15);
      if (cc < Nvalid) {
        float bs = bias ? bias[cc] : 0.f;
#pragma unroll
        for (int jj = 0; jj < 4; ++jj) {
          if (OUT16)
            ((u16*)Cv)[(size_t)(row + jj) * ldc + cc] = f2bf(acc[i][j][jj] + bs);
          else
            ((float*)Cv)[(size_t)(row + jj) * ldc + cc] = acc[i][j][jj] + bs;
        }
      }
    }
  }
}

// ---------------------------------------------------------------------------
// Persistent recurrence. Grid = 128 x 512, 1 block/CU.
// [0,32) H1 (32 cols) | [32,64) SCORE (1/batch) | [64,128) H0 (16 cols)
// Chain: H1(partials) -> SCORE(att) -> H0(h0) -> H1.  All coherent traffic
// packed wide (8/16B); weights LDS-resident or L2-streamed (plain loads).
// ---------------------------------------------------------------------------
__global__ __launch_bounds__(512, 1) void decoder_persistent(
    const u16* __restrict__ wdecb, const u16* __restrict__ w0eh,
    const u16* __restrict__ w1cat, const u16* __restrict__ encprojb,
    const u16* __restrict__ encW0T, const u16* __restrict__ embbt,
    const float* __restrict__ bias0, const float* __restrict__ bias1,
    const float* __restrict__ vw, const int* __restrict__ msk,
    u16* __restrict__ partials, u16* __restrict__ attbufB,
    u16* __restrict__ h0buf, u16* __restrict__ h1buf,
    u16* __restrict__ h1all, float* __restrict__ outattn, u32* flags)
{
  extern __shared__ char smem[];
  const int tid = threadIdx.x;
  const int bid = blockIdx.x;
  const int lane = tid & 63, wid = tid >> 6;
  const int l15 = lane & 15, l16 = (lane >> 4) << 3;
  const f32x4 zero4 = {0, 0, 0, 0};
  u32* h1flags = flags;                // 32 slots
  u32* scflags = flags + 32 * 32;      // 32 slots
  u32* h0flags = flags + 64 * 32;      // 64 slots

  if (bid < 32) {
    // ============ H1: h1 = tanh([h0|h1prev] @ W1^T + b1); decp partials =====
    const int n0 = bid * 32;
    u16* w1L = (u16*)smem;                      // [32][2056] u16 = 131584 B
    float* scr = (float*)(smem + 131584);       // [8][2][64][4] f32 = 16384 B
    u16* h1newL = (u16*)(smem + 147968);        // [32][32] u16 = 2048 B
    float* b1L = (float*)(smem + 150016);       // [32] f32
    {
      for (int c = tid; c < 8192; c += 512) {
        int r = c >> 8, seg = (c & 255) * 8;
        *(bf16x8*)&w1L[r * 2056 + seg] =
            *(const bf16x8*)&w1cat[(size_t)(n0 + r) * 2048 + seg];
      }
      if (tid < 32) b1L[tid] = bias1[n0 + tid];
      for (int c = tid; c < 1024; c += 512) {
        int b = c >> 5, n = c & 31;
        h1newL[c] = h1buf[(size_t)b * 1024 + n0 + n];   // init state (prep)
      }
    }
    __syncthreads();
    const int bt = wid >> 2, kq = wid & 3;
    const int ab = bt * 16 + l15;

    for (int t = -1; t < 64; ++t) {
      if (t >= 0) {
        poll_flags(h1flags, 32, (u32)(t + 1));
        const u16* hp = h1buf + (size_t)(t & 1) * 32768;
        f32x4 acc0 = zero4, acc1 = zero4;
        {   // early: h1prev (x-k 1024..2047)
          bf16x8 av[8];
#pragma unroll
          for (int ks = 0; ks < 8; ++ks)
            issue_lcoh(av[ks], hp + (size_t)ab * 1024 + kq * 256 + ks * 32 + l16);
          vm_wait0();
#pragma unroll
          for (int ks = 0; ks < 8; ++ks) {
            int kx = 1024 + kq * 256 + ks * 32 + l16;
            acc0 = MFMA_BF16(av[ks], *(const bf16x8*)&w1L[l15 * 2056 + kx], acc0);
            acc1 = MFMA_BF16(av[ks], *(const bf16x8*)&w1L[(16 + l15) * 2056 + kx], acc1);
          }
        }
        poll_flags(h0flags, 64, (u32)(t + 1));
        const u16* hn = h0buf + (size_t)((t + 1) & 1) * 32768;
        {   // late: h0 (x-k 0..1023)
          bf16x8 av[8];
#pragma unroll
          for (int ks = 0; ks < 8; ++ks)
            issue_lcoh(av[ks], hn + (size_t)ab * 1024 + kq * 256 + ks * 32 + l16);
          vm_wait0();
#pragma unroll
          for (int ks = 0; ks < 8; ++ks) {
            int kx = kq * 256 + ks * 32 + l16;
            acc0 = MFMA_BF16(av[ks], *(const bf16x8*)&w1L[l15 * 2056 + kx], acc0);
            acc1 = MFMA_BF16(av[ks], *(const bf16x8*)&w1L[(16 + l15) * 2056 + kx], acc1);
          }
        }
        *(f32x4*)&scr[((wid * 2 + 0) * 64 + lane) * 4] = acc0;
        *(f32x4*)&scr[((wid * 2 + 1) * 64 + lane) * 4] = acc1;
        __syncthreads();
        {   // combine + tanh -> h1newL
          int b = tid >> 4, n16 = tid & 15;
          int lanep = (((b & 15) >> 2) << 4) | n16;
          int r = b & 3, btc = b >> 4;
#pragma unroll
          for (int nt = 0; nt < 2; ++nt) {
            int n = nt * 16 + n16;
            float s = b1L[n];
#pragma unroll
            for (int q = 0; q < 4; ++q)
              s += scr[(((btc * 4 + q) * 2 + nt) * 64 + lanep) * 4 + r];
            h1newL[b * 32 + n] = f2bf(tanh_fast(s));
          }
        }
        __syncthreads();
        if (tid < 128) {   // wide stores: h1buf (coh) + h1all (plain)
          int b = tid >> 2, q = tid & 3;
          bf16x8 v8 = *(const bf16x8*)&h1newL[b * 32 + q * 8];
          scoh_dx4(h1buf + (size_t)((t + 1) & 1) * 32768 + (size_t)b * 1024 + n0 + q * 8, v8);
          *(bf16x8*)(h1all + ((size_t)b * 64 + t) * 1024 + n0 + q * 8) = v8;
        }
      }
      {   // decp partials: D[a][b], rank-32 chunk; Wdec slice streamed from L2
#pragma unroll
        for (int bt2 = 0; bt2 < 2; ++bt2) {
          bf16x8 hb = *(const bf16x8*)&h1newL[(bt2 * 16 + l15) * 32 + l16];
#pragma unroll
          for (int i = 0; i < 4; ++i) {
            int at = wid * 4 + i;
            bf16x8 wa = *(const bf16x8*)&wdecb[(size_t)(at * 16 + l15) * 1024 + n0 + l16];
            f32x4 c = MFMA_BF16(wa, hb, zero4);
            int a0 = at * 16 + ((lane >> 4) << 2);
            int bb = bt2 * 16 + l15;
            u32 lo = (u32)f2bf(c[0]) | ((u32)f2bf(c[1]) << 16);
            u32 hi = (u32)f2bf(c[2]) | ((u32)f2bf(c[3]) << 16);
            scoh_dx2(partials + ((size_t)bb * 32 + bid) * 512 + a0, lo, hi);
          }
        }
      }
      post_flag(h1flags + (size_t)bid * 32, (u32)(t + 2));
    }
  } else if (bid < 64) {
    // ============ SCORE: reduce partials -> dp; tanh scores; softmax ========
    const int b = bid - 32;
    u16* epL = (u16*)smem;                      // [128][520] u16 = 133120 B
    float* vwL = (float*)(smem + 133120);       // [512]
    float* red = (float*)(smem + 135168);       // [8][512] f32 = 16384 B
    float* decpL = (float*)(smem + 151552);     // [512]
    float* attF = (float*)(smem + 153600);      // [128]
    u16* attB = (u16*)(smem + 154112);          // [128]
    float* eL = (float*)(smem + 154368);        // [128]
    float* mkL = (float*)(smem + 154880);       // [128]
    float* sumL = (float*)(smem + 155392);      // [8]
    {
      for (int c = tid; c < 8192; c += 512)
        *(bf16x8*)&epL[(c >> 6) * 520 + (c & 63) * 8] =
            *(const bf16x8*)&encprojb[((size_t)b * 128 + (c >> 6)) * 512 + (c & 63) * 8];
      vwL[tid] = vw[tid];
      if (tid < 128) mkL[tid] = (float)msk[b * 128 + tid];
    }
    __syncthreads();
    for (int t = 0; t < 64; ++t) {
      poll_flags(h1flags, 32, (u32)(t + 1));
      {   // reduce 32 rank-chunks -> decpL
        const int a8 = tid & 63, hg = tid >> 6;
        const int a = a8 * 8;
        bf16x8 w[4];
#pragma unroll
        for (int i = 0; i < 4; ++i)
          issue_lcoh(w[i], partials + ((size_t)b * 32 + hg * 4 + i) * 512 + a);
        vm_wait0();
        float s[8];
#pragma unroll
        for (int e = 0; e < 8; ++e) {
          s[e] = bf2f((u16)w[0][e]) + bf2f((u16)w[1][e]) +
                 bf2f((u16)w[2][e]) + bf2f((u16)w[3][e]);
        }
#pragma unroll
        for (int e = 0; e < 8; ++e) red[hg * 512 + a + e] = s[e];
      }
      __syncthreads();
      {
        float s = 0.f;
#pragma unroll
        for (int hg = 0; hg < 8; ++hg) s += red[hg * 512 + tid];
        decpL[tid] = s;
      }
      __syncthreads();
      {   // scores
        const int s = tid >> 2, q = tid & 3;
        const u16* ep = &epL[s * 520 + q * 128];
        const float* dp = &decpL[q * 128];
        const float* vv = &vwL[q * 128];
        float a0 = 0.f, a1 = 0.f;
#pragma unroll
        for (int ii = 0; ii < 16; ++ii) {
          int i = (ii + q * 4) & 15;
          bf16x8 ev = *(const bf16x8*)(ep + i * 8);
#pragma unroll
          for (int e = 0; e < 8; e += 2) {
            float x0 = bf2f((u16)ev[e]) + dp[i * 8 + e];
            float x1 = bf2f((u16)ev[e + 1]) + dp[i * 8 + e + 1];
            a0 = fmaf(vv[i * 8 + e],     1.f - 2.f * rcp_fast(exp2_fast(x0) + 1.f), a0);
            a1 = fmaf(vv[i * 8 + e + 1], 1.f - 2.f * rcp_fast(exp2_fast(x1) + 1.f), a1);
          }
        }
        float acc = a0 + a1;
        acc += __shfl_xor(acc, 1);
        acc += __shfl_xor(acc, 2);
        float e = 0.f;
        if (q == 0) { e = (mkL[s] != 0.f) ? __expf(acc) : 0.f; eL[s] = e; }
        float ee = e;
#pragma unroll
        for (int off = 1; off < 64; off <<= 1) ee += __shfl_xor(ee, off);
        if (lane == 0) sumL[wid] = ee;
      }
      __syncthreads();
      {
        float tot = sumL[0] + sumL[1] + sumL[2] + sumL[3] +
                    sumL[4] + sumL[5] + sumL[6] + sumL[7];
        if (tid < 128) {
          float att = (tot > 0.f) ? eL[tid] * rcp_fast(tot) : 0.0078125f;
          attF[tid] = att;
          attB[tid] = f2bf(att);
        }
      }
      __syncthreads();
      if (tid < 32)
        *(f32x4*)(outattn + ((size_t)b * 64 + t) * 128 + tid * 4) = *(const f32x4*)&attF[tid * 4];
      if (tid < 16)
        scoh_dx4(attbufB + (size_t)b * 128 + tid * 8, *(const bf16x8*)&attB[tid * 8]);
      post_flag(scflags + (size_t)b * 32, (u32)(t + 1));
    }
  } else {
    // ============ H0: h0 = tanh(x@W0 + att.encW0T + b0), 16 cols =============
    const int h = bid - 64, j0 = h * 16;
    u16* e0L = (u16*)smem;                      // [16][4104] u16 = 131328 B
    float* attL = (float*)(smem + 131328);      // [32][128] f32 = 16384 B
    float* scrH = (float*)(smem + 147712);      // [8][64][4] f32 = 8192 B
    u16* h0newL = (u16*)(smem + 155904);        // [32][16] u16 = 1024 B
    float* b0L = (float*)(smem + 156928);       // [16]
    {
      for (int c = tid; c < 8192; c += 512) {
        int j = c >> 9, off = (c & 511) * 8;
        *(bf16x8*)&e0L[j * 4104 + off] =
            *(const bf16x8*)&encW0T[(size_t)(j0 + j) * 4096 + off];
      }
      if (tid < 16) b0L[tid] = bias0[j0 + tid];
    }
    __syncthreads();
    const int bt = wid >> 2, kq = wid & 3;
    const int ab = bt * 16 + l15;

    for (int t = 0; t < 64; ++t) {
      poll_flags(h0flags, 64, (u32)t);          // peers done step t-1
      {   // MFMA over x=[emb|h0prev], W0 streamed from L2
        bf16x8 xa[12], wb[12];
        const u16* hp = h0buf + (size_t)(t & 1) * 32768;
#pragma unroll
        for (int ks = 0; ks < 12; ++ks) {
          int kk = kq * 384 + ks * 32;
          if (kk < 512)
            xa[ks] = *(const bf16x8*)&embbt[((size_t)ab * 64 + t) * 512 + kk + l16];
          else
            issue_lcoh(xa[ks], hp + (size_t)ab * 1024 + (kk - 512) + l16);
          wb[ks] = *(const bf16x8*)&w0eh[(size_t)(j0 + l15) * 1536 + kk + l16];
        }
        vm_wait0();
        f32x4 acc = zero4;
#pragma unroll
        for (int ks = 0; ks < 12; ++ks) acc = MFMA_BF16(xa[ks], wb[ks], acc);
        *(f32x4*)&scrH[(wid * 64 + lane) * 4] = acc;
      }
      poll_flags(scflags, 32, (u32)(t + 1));    // att(t) ready
      {   // load att bf16 -> attL f32
        bf16x8 v;
        issue_lcoh(v, attbufB + tid * 8);
        vm_wait0();
#pragma unroll
        for (int e = 0; e < 8; ++e) attL[tid * 8 + e] = bf2f((u16)v[e]);
      }
      __syncthreads();
      {   // att-dot + combine + tanh
        int b = tid >> 4, j = tid & 15;
        const float* ar = &attL[b * 128];
        float adot = 0.f;
#pragma unroll
        for (int c8 = 0; c8 < 16; ++c8) {
          bf16x8 ev = *(const bf16x8*)&e0L[j * 4104 + b * 128 + c8 * 8];
#pragma unroll
          for (int e = 0; e < 8; ++e) adot = fmaf(ar[c8 * 8 + e], bf2f((u16)ev[e]), adot);
        }
        int lanep = (((b & 15) >> 2) << 4) | j;
        int r = b & 3, btc = b >> 4;
        float s = adot + b0L[j];
#pragma unroll
        for (int q = 0; q < 4; ++q)
          s += scrH[((btc * 4 + q) * 64 + lanep) * 4 + r];
        h0newL[b * 16 + j] = f2bf(tanh_fast(s));
      }
      __syncthreads();
      if (tid < 64) {
        int b = tid >> 1, half = tid & 1;
        scoh_dx4(h0buf + (size_t)((t + 1) & 1) * 32768 + (size_t)b * 1024 + j0 + half * 8,
                 *(const bf16x8*)&h0newL[b * 16 + half * 8]);
      }
      post_flag(h0flags + (size_t)h * 32, (u32)(t + 1));
    }
  }
}

// ---------------------------------------------------------------------------
extern "C" void kernel_launch(void* const* d_in, const int* in_sizes, int n_in,
                              void* d_out, int out_size, void* d_ws, size_t ws_size,
                              hipStream_t stream)
{
  const int*   yin  = (const int*)d_in[0];
  const float* enc  = (const float*)d_in[1];
  const float* dih  = (const float*)d_in[2];
  const int*   msk  = (const int*)d_in[3];
  const float* emb  = (const float*)d_in[4];
  const float* wenc = (const float*)d_in[5];
  const float* wdec = (const float*)d_in[6];
  const float* vw   = (const float*)d_in[7];
  const float* wih0 = (const float*)d_in[8];
  const float* whh0 = (const float*)d_in[9];
  const float* bih0 = (const float*)d_in[10];
  const float* bhh0 = (const float*)d_in[11];
  const float* wih1 = (const float*)d_in[12];
  const float* whh1 = (const float*)d_in[13];
  const float* bih1 = (const float*)d_in[14];
  const float* bhh1 = (const float*)d_in[15];
  const float* fcw  = (const float*)d_in[16];
  const float* fcb  = (const float*)d_in[17];

  char* ws = (char*)d_ws;
  size_t off = 0;
  auto alloc = [&](size_t bytes) {
    char* p = ws + off; off += (bytes + 255) & ~(size_t)255; return p;
  };
  u16*   fcwb     = (u16*)alloc(32768000ULL * 2);
  u16*   encb     = (u16*)alloc(4194304ULL * 2);
  u16*   wencb    = (u16*)alloc(524288ULL * 2);
  u16*   wdecb    = (u16*)alloc(524288ULL * 2);
  u16*   w0eh     = (u16*)alloc(1572864ULL * 2);
  u16*   w0ctx    = (u16*)alloc(1048576ULL * 2);
  u16*   w1cat    = (u16*)alloc(2097152ULL * 2);
  u16*   embbt    = (u16*)alloc(1048576ULL * 2);
  u16*   encprojb = (u16*)alloc(2097152ULL * 2);
  u16*   encW0T   = (u16*)alloc(4194304ULL * 2);
  u16*   partials = (u16*)alloc(524288ULL * 2);     // [32 b][32 hh][512 a]
  u16*   attbufB  = (u16*)alloc(4096ULL * 2);       // [32 b][128 s] bf16
  u16*   h0buf    = (u16*)alloc(65536ULL * 2);
  u16*   h1buf    = (u16*)alloc(65536ULL * 2);
  u16*   h1all    = (u16*)alloc(2097152ULL * 2);
  float* bias0    = (float*)alloc(1024ULL * 4);
  float* bias1    = (float*)alloc(1024ULL * 4);
  u32*   flags    = (u32*)alloc(16384ULL);
  if (off > ws_size) return;  // workspace too small -> visible failure

  float* outlog  = (float*)d_out;                 // [2048][31999]
  float* outattn = outlog + 65533952ULL;          // [32][64][128]

  (void)hipMemsetAsync(flags, 0, 16384, stream);

  prep_kernel<<<2048, 256, 0, stream>>>(
      fcw, enc, wenc, wdec, wih0, whh0, wih1, whh1,
      bih0, bhh0, bih1, bhh1, emb, yin, dih,
      fcwb, encb, wencb, wdecb, w0eh, w0ctx, w1cat, embbt, bias0, bias1,
      h0buf, h1buf);

  // enc_proj (prescaled, bf16): [4096][512] = encb @ wencb^T
  gemm128<1><<<32 * 4, 256, 0, stream>>>(encb, wencb, nullptr, encprojb,
                                         1024, 512, 512, 4);
  // encW0T (bf16): [1024 j][4096 bs] = w0ctx @ encb^T
  gemm128<1><<<8 * 32, 256, 0, stream>>>(w0ctx, encb, nullptr, encW0T,
                                         1024, 4096, 4096, 32);

  (void)hipFuncSetAttribute((const void*)decoder_persistent,
                            hipFuncAttributeMaxDynamicSharedMemorySize, 157184);
  decoder_persistent<<<128, 512, 157184, stream>>>(
      wdecb, w0eh, w1cat, encprojb, encW0T, embbt, bias0, bias1,
      vw, msk, partials, attbufB, h0buf, h1buf, h1all, outattn, flags);

  // logits: [2048][31999] = h1all @ fcwb^T + fc_b
  gemm128<0><<<16 * 250, 256, 0, stream>>>(h1all, fcwb, fcb, outlog,
                                           1024, 31999, 31999, 250);
}

// Round 8
// 1629.222 us; speedup vs baseline: 1.1863x; 1.1863x over previous
//
#include <hip/hip_runtime.h>

typedef unsigned short u16;
typedef unsigned int u32;
typedef __attribute__((ext_vector_type(8))) short bf16x8;
typedef __attribute__((ext_vector_type(4))) float f32x4;
typedef __attribute__((ext_vector_type(2))) unsigned int u32x2;

#define MFMA_BF16(a,b,c) __builtin_amdgcn_mfma_f32_16x16x32_bf16((a),(b),(c),0,0,0)

__device__ __forceinline__ u16 f2bf(float f) {
  union { float f; u32 u; } v; v.f = f;
  u32 r = v.u + 0x7FFFu + ((v.u >> 16) & 1u);
  return (u16)(r >> 16);
}
__device__ __forceinline__ float bf2f(u16 h) {
  union { u32 u; float f; } v; v.u = ((u32)h) << 16; return v.f;
}
__device__ __forceinline__ float tanh_fast(float x) {
  float e = __expf(2.0f * x);
  return 1.0f - 2.0f / (e + 1.0f);
}
__device__ __forceinline__ float exp2_fast(float x) {
  float r; asm("v_exp_f32 %0, %1" : "=v"(r) : "v"(x)); return r;
}
__device__ __forceinline__ float rcp_fast(float x) {
  float r; asm("v_rcp_f32 %0, %1" : "=v"(r) : "v"(x)); return r;
}

// ---- coherent (cross-XCD) ld/st ------------------------------------------
__device__ __forceinline__ void issue_lcoh(bf16x8& v, const u16* p) {
  asm volatile("global_load_dwordx4 %0, %1, off sc0 sc1" : "=v"(v) : "v"(p));
}
__device__ __forceinline__ void vm_wait0() {
  asm volatile("s_waitcnt vmcnt(0)" ::: "memory");
  __builtin_amdgcn_sched_barrier(0);
}
__device__ __forceinline__ void scoh_u32(u32* p, u32 v) {
  asm volatile("global_store_dword %0, %1, off sc0 sc1" :: "v"(p), "v"(v) : "memory");
}
__device__ __forceinline__ void scoh_dx2(u16* p, u32 lo, u32 hi) {
  u32x2 v; v.x = lo; v.y = hi;
  asm volatile("global_store_dwordx2 %0, %1, off sc0 sc1" :: "v"(p), "v"(v) : "memory");
}
__device__ __forceinline__ void scoh_dx4(u16* p, bf16x8 v) {
  asm volatile("global_store_dwordx4 %0, %1, off sc0 sc1" :: "v"(p), "v"(v) : "memory");
}
__device__ __forceinline__ u32 poll_load(const u32* p) {
  u32 v;
  asm volatile("global_load_dword %0, %1, off sc0 sc1\n\ts_waitcnt vmcnt(0)"
               : "=v"(v) : "v"(p) : "memory");
  return v;
}

// Poll P per-producer flag slots (128B apart) until all >= target.
__device__ __forceinline__ void poll_flags(const u32* base, int P, u32 target) {
  if (target == 0u) return;
  if ((threadIdx.x >> 6) == 0) {
    const int lane = threadIdx.x & 63;
    const u32* s0 = base + (size_t)(lane & (P - 1)) * 32;
    for (;;) {
      u32 v0 = poll_load(s0);
      if (__all(v0 >= target)) break;
      __builtin_amdgcn_s_sleep(1);
    }
  }
  __syncthreads();
  __builtin_amdgcn_sched_barrier(0);
}
__device__ __forceinline__ void post_flag(u32* slot, u32 val) {
  asm volatile("s_waitcnt vmcnt(0)" ::: "memory");
  __syncthreads();
  if (threadIdx.x == 0) scoh_u32(slot, val);
}

// ---------------------------------------------------------------------------
// Prep  (fcwb now padded to 32768 rows)
// ---------------------------------------------------------------------------
__global__ void prep_kernel(
    const float* __restrict__ fcw, const float* __restrict__ enc,
    const float* __restrict__ wenc, const float* __restrict__ wdec,
    const float* __restrict__ wih0, const float* __restrict__ whh0,
    const float* __restrict__ wih1, const float* __restrict__ whh1,
    const float* __restrict__ bih0, const float* __restrict__ bhh0,
    const float* __restrict__ bih1, const float* __restrict__ bhh1,
    const float* __restrict__ emb, const int* __restrict__ yin,
    const float* __restrict__ dih,
    u16* __restrict__ fcwb, u16* __restrict__ encb, u16* __restrict__ wencb,
    u16* __restrict__ wdecb, u16* __restrict__ w0eh, u16* __restrict__ w0ctx,
    u16* __restrict__ w1cat, u16* __restrict__ embbt,
    float* __restrict__ bias0, float* __restrict__ bias1,
    u16* __restrict__ h0buf0, u16* __restrict__ h1buf0)
{
  const float SCL = 2.8853900817779268f;   // 2*log2(e)
  const long long total = 44632064LL;
  for (long long i = (long long)blockIdx.x * 256 + threadIdx.x; i < total;
       i += (long long)gridDim.x * 256) {
    if (i < 33554432LL) {                    // fc_w bf16, padded to 32768 rows
      int r = (int)(i >> 10), c = (int)(i & 1023);
      fcwb[i] = (r < 31999) ? f2bf(fcw[(long long)r * 1024 + c]) : (u16)0;
    } else if (i < 37748736LL) {
      long long j = i - 33554432LL; encb[j] = f2bf(enc[j]);
    } else if (i < 38273024LL) {
      long long j = i - 37748736LL; wencb[j] = f2bf(wenc[j] * SCL);
    } else if (i < 38797312LL) {
      long long j = i - 38273024LL; wdecb[j] = f2bf(wdec[j] * SCL);
    } else if (i < 40370176LL) {             // w0eh [1024][1536]: [Wih0_emb|Whh0]
      long long j = i - 38797312LL;
      int r = (int)(j / 1536), c = (int)(j % 1536);
      float v = (c < 512) ? wih0[(long long)r * 1536 + c]
                          : whh0[(long long)r * 1024 + (c - 512)];
      w0eh[j] = f2bf(v);
    } else if (i < 41418752LL) {             // w0ctx [1024][1024] = Wih0[:,512:1536]
      long long j = i - 40370176LL;
      int r = (int)(j >> 10), e = (int)(j & 1023);
      w0ctx[j] = f2bf(wih0[(long long)r * 1536 + 512 + e]);
    } else if (i < 43515904LL) {             // w1cat [1024][2048]: [Wih1|Whh1]
      long long j = i - 41418752LL;
      int r = (int)(j >> 11), c = (int)(j & 2047);
      w1cat[j] = f2bf(c < 1024 ? wih1[(r << 10) + c] : whh1[(r << 10) + (c - 1024)]);
    } else if (i < 44564480LL) {             // embedding gather
      long long j = i - 43515904LL;
      int bt = (int)(j >> 9), c = (int)(j & 511);
      int y = yin[bt];
      embbt[j] = f2bf(emb[(long long)y * 512 + c]);
    } else if (i < 44565504LL) {
      int j = (int)(i - 44564480LL); bias0[j] = bih0[j] + bhh0[j];
    } else if (i < 44566528LL) {
      int j = (int)(i - 44565504LL); bias1[j] = bih1[j] + bhh1[j];
    } else if (i < 44599296LL) {
      int j = (int)(i - 44566528LL); h0buf0[j] = f2bf(dih[j]);
    } else {
      int j = (int)(i - 44599296LL); h1buf0[j] = f2bf(dih[32768 + j]);
    }
  }
}

// ---------------------------------------------------------------------------
// Generic 128x128-tile bf16 MFMA GEMM (bf16 out)
// ---------------------------------------------------------------------------
__global__ __launch_bounds__(256) void gemm128b(
    const u16* __restrict__ A, const u16* __restrict__ Bm,
    u16* __restrict__ Cv, int K, int ldc, int ntN)
{
  __shared__ u16 As[128 * 32];
  __shared__ u16 Bs[128 * 32];
  const int tid = threadIdx.x;
  const int bid = blockIdx.x;
  const int tM = bid / ntN, tN = bid - tM * ntN;
  const int m0 = tM * 128, n0 = tN * 128;
  const int lane = tid & 63, wid = tid >> 6;
  const int wm = wid >> 1, wn = wid & 1;
  const int srow = tid >> 1, scol = (tid & 1) * 16;

  const u16* gA = A + (size_t)(m0 + srow) * K + scol;
  const u16* gB = Bm + (size_t)(n0 + srow) * K + scol;
  u16* sA = &As[srow * 32 + scol];
  u16* sB = &Bs[srow * 32 + scol];

  f32x4 acc[4][4];
#pragma unroll
  for (int i = 0; i < 4; ++i)
#pragma unroll
    for (int j = 0; j < 4; ++j) acc[i][j] = (f32x4){0, 0, 0, 0};

  const int aoff = (wm * 64 + (lane & 15)) * 32 + ((lane >> 4) << 3);
  const int boff = (wn * 64 + (lane & 15)) * 32 + ((lane >> 4) << 3);

  for (int k0 = 0; k0 < K; k0 += 32) {
    bf16x8 va0 = *(const bf16x8*)(gA + k0);
    bf16x8 va1 = *(const bf16x8*)(gA + k0 + 8);
    bf16x8 vb0 = *(const bf16x8*)(gB + k0);
    bf16x8 vb1 = *(const bf16x8*)(gB + k0 + 8);
    __syncthreads();
    *((bf16x8*)sA) = va0;  *((bf16x8*)(sA + 8)) = va1;
    *((bf16x8*)sB) = vb0;  *((bf16x8*)(sB + 8)) = vb1;
    __syncthreads();
    bf16x8 af[4], bfj[4];
#pragma unroll
    for (int i = 0; i < 4; ++i) af[i] = *(const bf16x8*)&As[aoff + i * 512];
#pragma unroll
    for (int j = 0; j < 4; ++j) bfj[j] = *(const bf16x8*)&Bs[boff + j * 512];
#pragma unroll
    for (int i = 0; i < 4; ++i)
#pragma unroll
      for (int j = 0; j < 4; ++j)
        acc[i][j] = MFMA_BF16(af[i], bfj[j], acc[i][j]);
  }

#pragma unroll
  for (int i = 0; i < 4; ++i) {
#pragma unroll
    for (int j = 0; j < 4; ++j) {
      int row = m0 + wm * 64 + i * 16 + ((lane >> 4) << 2);
      int cc = n0 + wn * 64 + j * 16 + (lane & 15);
#pragma unroll
      for (int jj = 0; jj < 4; ++jj)
        Cv[(size_t)(row + jj) * ldc + cc] = f2bf(acc[i][j][jj]);
    }
  }
}

// ---------------------------------------------------------------------------
// Persistent. Grid = 256 x 512, 1 block/CU (LDS-capped).
// [0,32) H1 | [32,64) SCORE | [64,128) H0 | [128,256) FC (passive consumers)
// ---------------------------------------------------------------------------
__global__ __launch_bounds__(512, 1) void decoder_persistent(
    const u16* __restrict__ wdecb, const u16* __restrict__ w0eh,
    const u16* __restrict__ w1cat, const u16* __restrict__ encprojb,
    const u16* __restrict__ encW0T, const u16* __restrict__ embbt,
    const float* __restrict__ bias0, const float* __restrict__ bias1,
    const float* __restrict__ vw, const int* __restrict__ msk,
    const u16* __restrict__ fcwb, const float* __restrict__ fcb,
    u16* __restrict__ partials, u16* __restrict__ attbufB,
    u16* __restrict__ h0buf, u16* __restrict__ h1buf,
    u16* __restrict__ h1all, float* __restrict__ outattn,
    float* __restrict__ outlog, u32* flags)
{
  extern __shared__ char smem[];
  const int tid = threadIdx.x;
  const int bid = blockIdx.x;
  const int lane = tid & 63, wid = tid >> 6;
  const int l15 = lane & 15, l16 = (lane >> 4) << 3;
  const f32x4 zero4 = {0, 0, 0, 0};
  u32* h1flags = flags;                // 32 slots
  u32* scflags = flags + 32 * 32;      // 32 slots
  u32* h0flags = flags + 64 * 32;      // 64 slots

  if (bid < 32) {
    // ============ H1: h1 = tanh([h0|h1prev] @ W1^T + b1); decp partials =====
    const int n0 = bid * 32;
    u16* w1L = (u16*)smem;                      // [32][2056] u16
    float* scr = (float*)(smem + 131584);       // [8][2][64][4] f32
    u16* h1newL = (u16*)(smem + 147968);        // [32][32] u16
    float* b1L = (float*)(smem + 150016);       // [32]
    {
      for (int c = tid; c < 8192; c += 512) {
        int r = c >> 8, seg = (c & 255) * 8;
        *(bf16x8*)&w1L[r * 2056 + seg] =
            *(const bf16x8*)&w1cat[(size_t)(n0 + r) * 2048 + seg];
      }
      if (tid < 32) b1L[tid] = bias1[n0 + tid];
      for (int c = tid; c < 1024; c += 512) {
        int b = c >> 5, n = c & 31;
        h1newL[c] = h1buf[(size_t)b * 1024 + n0 + n];
      }
    }
    __syncthreads();
    const int bt = wid >> 2, kq = wid & 3;
    const int ab = bt * 16 + l15;

    for (int t = -1; t < 64; ++t) {
      if (t >= 0) {
        poll_flags(h1flags, 32, (u32)(t + 1));
        const u16* hp = h1buf + (size_t)(t & 1) * 32768;
        f32x4 acc0 = zero4, acc1 = zero4;
        {
          bf16x8 av[8];
#pragma unroll
          for (int ks = 0; ks < 8; ++ks)
            issue_lcoh(av[ks], hp + (size_t)ab * 1024 + kq * 256 + ks * 32 + l16);
          vm_wait0();
#pragma unroll
          for (int ks = 0; ks < 8; ++ks) {
            int kx = 1024 + kq * 256 + ks * 32 + l16;
            acc0 = MFMA_BF16(av[ks], *(const bf16x8*)&w1L[l15 * 2056 + kx], acc0);
            acc1 = MFMA_BF16(av[ks], *(const bf16x8*)&w1L[(16 + l15) * 2056 + kx], acc1);
          }
        }
        poll_flags(h0flags, 64, (u32)(t + 1));
        const u16* hn = h0buf + (size_t)((t + 1) & 1) * 32768;
        {
          bf16x8 av[8];
#pragma unroll
          for (int ks = 0; ks < 8; ++ks)
            issue_lcoh(av[ks], hn + (size_t)ab * 1024 + kq * 256 + ks * 32 + l16);
          vm_wait0();
#pragma unroll
          for (int ks = 0; ks < 8; ++ks) {
            int kx = kq * 256 + ks * 32 + l16;
            acc0 = MFMA_BF16(av[ks], *(const bf16x8*)&w1L[l15 * 2056 + kx], acc0);
            acc1 = MFMA_BF16(av[ks], *(const bf16x8*)&w1L[(16 + l15) * 2056 + kx], acc1);
          }
        }
        *(f32x4*)&scr[((wid * 2 + 0) * 64 + lane) * 4] = acc0;
        *(f32x4*)&scr[((wid * 2 + 1) * 64 + lane) * 4] = acc1;
        __syncthreads();
        {
          int b = tid >> 4, n16 = tid & 15;
          int lanep = (((b & 15) >> 2) << 4) | n16;
          int r = b & 3, btc = b >> 4;
#pragma unroll
          for (int nt = 0; nt < 2; ++nt) {
            int n = nt * 16 + n16;
            float s = b1L[n];
#pragma unroll
            for (int q = 0; q < 4; ++q)
              s += scr[(((btc * 4 + q) * 2 + nt) * 64 + lanep) * 4 + r];
            h1newL[b * 32 + n] = f2bf(tanh_fast(s));
          }
        }
        __syncthreads();
        if (tid < 128) {   // wide coherent stores: h1buf + h1all (FC reads both)
          int b = tid >> 2, q = tid & 3;
          bf16x8 v8 = *(const bf16x8*)&h1newL[b * 32 + q * 8];
          scoh_dx4(h1buf + (size_t)((t + 1) & 1) * 32768 + (size_t)b * 1024 + n0 + q * 8, v8);
          scoh_dx4(h1all + ((size_t)b * 64 + t) * 1024 + n0 + q * 8, v8);
        }
      }
      {   // decp partials
#pragma unroll
        for (int bt2 = 0; bt2 < 2; ++bt2) {
          bf16x8 hb = *(const bf16x8*)&h1newL[(bt2 * 16 + l15) * 32 + l16];
#pragma unroll
          for (int i = 0; i < 4; ++i) {
            int at = wid * 4 + i;
            bf16x8 wa = *(const bf16x8*)&wdecb[(size_t)(at * 16 + l15) * 1024 + n0 + l16];
            f32x4 c = MFMA_BF16(wa, hb, zero4);
            int a0 = at * 16 + ((lane >> 4) << 2);
            int bb = bt2 * 16 + l15;
            u32 lo = (u32)f2bf(c[0]) | ((u32)f2bf(c[1]) << 16);
            u32 hi = (u32)f2bf(c[2]) | ((u32)f2bf(c[3]) << 16);
            scoh_dx2(partials + ((size_t)bb * 32 + bid) * 512 + a0, lo, hi);
          }
        }
      }
      post_flag(h1flags + (size_t)bid * 32, (u32)(t + 2));
    }
  } else if (bid < 64) {
    // ============ SCORE ======================================================
    const int b = bid - 32;
    u16* epL = (u16*)smem;                      // [128][520]
    float* vwL = (float*)(smem + 133120);
    float* red = (float*)(smem + 135168);       // [8][512]
    float* decpL = (float*)(smem + 151552);
    float* attF = (float*)(smem + 153600);
    u16* attB = (u16*)(smem + 154112);
    float* eL = (float*)(smem + 154368);
    float* mkL = (float*)(smem + 154880);
    float* sumL = (float*)(smem + 155392);
    {
      for (int c = tid; c < 8192; c += 512)
        *(bf16x8*)&epL[(c >> 6) * 520 + (c & 63) * 8] =
            *(const bf16x8*)&encprojb[((size_t)b * 128 + (c >> 6)) * 512 + (c & 63) * 8];
      vwL[tid] = vw[tid];
      if (tid < 128) mkL[tid] = (float)msk[b * 128 + tid];
    }
    __syncthreads();
    for (int t = 0; t < 64; ++t) {
      poll_flags(h1flags, 32, (u32)(t + 1));
      {
        const int a8 = tid & 63, hg = tid >> 6;
        const int a = a8 * 8;
        bf16x8 w[4];
#pragma unroll
        for (int i = 0; i < 4; ++i)
          issue_lcoh(w[i], partials + ((size_t)b * 32 + hg * 4 + i) * 512 + a);
        vm_wait0();
#pragma unroll
        for (int e = 0; e < 8; ++e)
          red[hg * 512 + a + e] = bf2f((u16)w[0][e]) + bf2f((u16)w[1][e]) +
                                  bf2f((u16)w[2][e]) + bf2f((u16)w[3][e]);
      }
      __syncthreads();
      {
        float s = 0.f;
#pragma unroll
        for (int hg = 0; hg < 8; ++hg) s += red[hg * 512 + tid];
        decpL[tid] = s;
      }
      __syncthreads();
      {
        const int s = tid >> 2, q = tid & 3;
        const u16* ep = &epL[s * 520 + q * 128];
        const float* dp = &decpL[q * 128];
        const float* vv = &vwL[q * 128];
        float a0 = 0.f, a1 = 0.f;
#pragma unroll
        for (int ii = 0; ii < 16; ++ii) {
          int i = (ii + q * 4) & 15;
          bf16x8 ev = *(const bf16x8*)(ep + i * 8);
#pragma unroll
          for (int e = 0; e < 8; e += 2) {
            float x0 = bf2f((u16)ev[e]) + dp[i * 8 + e];
            float x1 = bf2f((u16)ev[e + 1]) + dp[i * 8 + e + 1];
            a0 = fmaf(vv[i * 8 + e],     1.f - 2.f * rcp_fast(exp2_fast(x0) + 1.f), a0);
            a1 = fmaf(vv[i * 8 + e + 1], 1.f - 2.f * rcp_fast(exp2_fast(x1) + 1.f), a1);
          }
        }
        float acc = a0 + a1;
        acc += __shfl_xor(acc, 1);
        acc += __shfl_xor(acc, 2);
        float e = 0.f;
        if (q == 0) { e = (mkL[s] != 0.f) ? __expf(acc) : 0.f; eL[s] = e; }
        float ee = e;
#pragma unroll
        for (int off = 1; off < 64; off <<= 1) ee += __shfl_xor(ee, off);
        if (lane == 0) sumL[wid] = ee;
      }
      __syncthreads();
      {
        float tot = sumL[0] + sumL[1] + sumL[2] + sumL[3] +
                    sumL[4] + sumL[5] + sumL[6] + sumL[7];
        if (tid < 128) {
          float att = (tot > 0.f) ? eL[tid] * rcp_fast(tot) : 0.0078125f;
          attF[tid] = att;
          attB[tid] = f2bf(att);
        }
      }
      __syncthreads();
      if (tid < 32)
        *(f32x4*)(outattn + ((size_t)b * 64 + t) * 128 + tid * 4) = *(const f32x4*)&attF[tid * 4];
      if (tid < 16)
        scoh_dx4(attbufB + (size_t)b * 128 + tid * 8, *(const bf16x8*)&attB[tid * 8]);
      post_flag(scflags + (size_t)b * 32, (u32)(t + 1));
    }
  } else if (bid < 128) {
    // ============ H0 =========================================================
    const int h = bid - 64, j0 = h * 16;
    u16* e0L = (u16*)smem;                      // [16][4104]
    float* attL = (float*)(smem + 131328);      // [32][128]
    float* scrH = (float*)(smem + 147712);      // [8][64][4]
    u16* h0newL = (u16*)(smem + 155904);        // [32][16]
    float* b0L = (float*)(smem + 156928);
    {
      for (int c = tid; c < 8192; c += 512) {
        int j = c >> 9, off = (c & 511) * 8;
        *(bf16x8*)&e0L[j * 4104 + off] =
            *(const bf16x8*)&encW0T[(size_t)(j0 + j) * 4096 + off];
      }
      if (tid < 16) b0L[tid] = bias0[j0 + tid];
    }
    __syncthreads();
    const int bt = wid >> 2, kq = wid & 3;
    const int ab = bt * 16 + l15;

    for (int t = 0; t < 64; ++t) {
      poll_flags(h0flags, 64, (u32)t);
      {
        bf16x8 xa[12], wb[12];
        const u16* hp = h0buf + (size_t)(t & 1) * 32768;
#pragma unroll
        for (int ks = 0; ks < 12; ++ks) {
          int kk = kq * 384 + ks * 32;
          if (kk < 512)
            xa[ks] = *(const bf16x8*)&embbt[((size_t)ab * 64 + t) * 512 + kk + l16];
          else
            issue_lcoh(xa[ks], hp + (size_t)ab * 1024 + (kk - 512) + l16);
          wb[ks] = *(const bf16x8*)&w0eh[(size_t)(j0 + l15) * 1536 + kk + l16];
        }
        vm_wait0();
        f32x4 acc = zero4;
#pragma unroll
        for (int ks = 0; ks < 12; ++ks) acc = MFMA_BF16(xa[ks], wb[ks], acc);
        *(f32x4*)&scrH[(wid * 64 + lane) * 4] = acc;
      }
      poll_flags(scflags, 32, (u32)(t + 1));
      {
        bf16x8 v;
        issue_lcoh(v, attbufB + tid * 8);
        vm_wait0();
#pragma unroll
        for (int e = 0; e < 8; ++e) attL[tid * 8 + e] = bf2f((u16)v[e]);
      }
      __syncthreads();
      {
        int b = tid >> 4, j = tid & 15;
        const float* ar = &attL[b * 128];
        float adot = 0.f;
#pragma unroll
        for (int c8 = 0; c8 < 16; ++c8) {
          bf16x8 ev = *(const bf16x8*)&e0L[j * 4104 + b * 128 + c8 * 8];
#pragma unroll
          for (int e = 0; e < 8; ++e) adot = fmaf(ar[c8 * 8 + e], bf2f((u16)ev[e]), adot);
        }
        int lanep = (((b & 15) >> 2) << 4) | j;
        int r = b & 3, btc = b >> 4;
        float s = adot + b0L[j];
#pragma unroll
        for (int q = 0; q < 4; ++q)
          s += scrH[((btc * 4 + q) * 64 + lanep) * 4 + r];
        h0newL[b * 16 + j] = f2bf(tanh_fast(s));
      }
      __syncthreads();
      if (tid < 64) {
        int b = tid >> 1, half = tid & 1;
        scoh_dx4(h0buf + (size_t)((t + 1) & 1) * 32768 + (size_t)b * 1024 + j0 + half * 8,
                 *(const bf16x8*)&h0newL[b * 16 + half * 8]);
      }
      post_flag(h0flags + (size_t)h * 32, (u32)(t + 1));
    }
  } else {
    // ============ FC: logits rows for step t as h1(t) appears ================
    const int f = bid - 128;
    const int n0g = f * 256;
    u16* aL = (u16*)smem;                       // [32][1024] bf16 = 64 KB
    for (int t = 0; t < 64; ++t) {
      if ((tid >> 6) == 0) {                    // wait h1(t) drained (flag t+2)
        const u32* s0 = h1flags + (size_t)(lane & 31) * 32;
        for (;;) {
          u32 v0 = poll_load(s0);
          if (__all(v0 >= (u32)(t + 2))) break;
          __builtin_amdgcn_s_sleep(8);
        }
      }
      __syncthreads();
      __builtin_amdgcn_sched_barrier(0);
      {   // A(t) = h1(t) rows -> LDS (coherent)
        int b = tid >> 4, ks = (tid & 15) * 64;
        bf16x8 v[8];
        const u16* src = h1all + ((size_t)b * 64 + t) * 1024 + ks;
#pragma unroll
        for (int i = 0; i < 8; ++i) issue_lcoh(v[i], src + i * 8);
        vm_wait0();
#pragma unroll
        for (int i = 0; i < 8; ++i) *(bf16x8*)&aL[b * 1024 + ks + i * 8] = v[i];
      }
      __syncthreads();
      f32x4 acc00 = zero4, acc01 = zero4, acc10 = zero4, acc11 = zero4;
      const int nt0 = wid * 2;
      const u16* brow0 = fcwb + (size_t)(n0g + (nt0 + 0) * 16 + l15) * 1024;
      const u16* brow1 = fcwb + (size_t)(n0g + (nt0 + 1) * 16 + l15) * 1024;
#pragma unroll 4
      for (int kk = 0; kk < 32; ++kk) {
        int ko = kk * 32 + l16;
        bf16x8 a0 = *(const bf16x8*)&aL[l15 * 1024 + ko];
        bf16x8 a1 = *(const bf16x8*)&aL[(16 + l15) * 1024 + ko];
        bf16x8 b0 = *(const bf16x8*)(brow0 + ko);
        bf16x8 b1 = *(const bf16x8*)(brow1 + ko);
        acc00 = MFMA_BF16(a0, b0, acc00);
        acc10 = MFMA_BF16(a1, b0, acc10);
        acc01 = MFMA_BF16(a0, b1, acc01);
        acc11 = MFMA_BF16(a1, b1, acc11);
      }
      __syncthreads();
      {
        const int rq = (lane >> 4) << 2;
#pragma unroll
        for (int ntl = 0; ntl < 2; ++ntl) {
          int col = n0g + (nt0 + ntl) * 16 + l15;
          if (col < 31999) {
            float bs = fcb[col];
            f32x4 c0 = ntl ? acc01 : acc00;
            f32x4 c1 = ntl ? acc11 : acc10;
#pragma unroll
            for (int j = 0; j < 4; ++j) {
              outlog[(size_t)((rq + j) * 64 + t) * 31999 + col] = c0[j] + bs;
              outlog[(size_t)((16 + rq + j) * 64 + t) * 31999 + col] = c1[j] + bs;
            }
          }
        }
      }
    }
  }
}

// ---------------------------------------------------------------------------
extern "C" void kernel_launch(void* const* d_in, const int* in_sizes, int n_in,
                              void* d_out, int out_size, void* d_ws, size_t ws_size,
                              hipStream_t stream)
{
  const int*   yin  = (const int*)d_in[0];
  const float* enc  = (const float*)d_in[1];
  const float* dih  = (const float*)d_in[2];
  const int*   msk  = (const int*)d_in[3];
  const float* emb  = (const float*)d_in[4];
  const float* wenc = (const float*)d_in[5];
  const float* wdec = (const float*)d_in[6];
  const float* vw   = (const float*)d_in[7];
  const float* wih0 = (const float*)d_in[8];
  const float* whh0 = (const float*)d_in[9];
  const float* bih0 = (const float*)d_in[10];
  const float* bhh0 = (const float*)d_in[11];
  const float* wih1 = (const float*)d_in[12];
  const float* whh1 = (const float*)d_in[13];
  const float* bih1 = (const float*)d_in[14];
  const float* bhh1 = (const float*)d_in[15];
  const float* fcw  = (const float*)d_in[16];
  const float* fcb  = (const float*)d_in[17];

  char* ws = (char*)d_ws;
  size_t off = 0;
  auto alloc = [&](size_t bytes) {
    char* p = ws + off; off += (bytes + 255) & ~(size_t)255; return p;
  };
  u16*   fcwb     = (u16*)alloc(33554432ULL * 2);   // [32768][1024]
  u16*   encb     = (u16*)alloc(4194304ULL * 2);
  u16*   wencb    = (u16*)alloc(524288ULL * 2);
  u16*   wdecb    = (u16*)alloc(524288ULL * 2);
  u16*   w0eh     = (u16*)alloc(1572864ULL * 2);
  u16*   w0ctx    = (u16*)alloc(1048576ULL * 2);
  u16*   w1cat    = (u16*)alloc(2097152ULL * 2);
  u16*   embbt    = (u16*)alloc(1048576ULL * 2);
  u16*   encprojb = (u16*)alloc(2097152ULL * 2);
  u16*   encW0T   = (u16*)alloc(4194304ULL * 2);
  u16*   partials = (u16*)alloc(524288ULL * 2);
  u16*   attbufB  = (u16*)alloc(4096ULL * 2);
  u16*   h0buf    = (u16*)alloc(65536ULL * 2);
  u16*   h1buf    = (u16*)alloc(65536ULL * 2);
  u16*   h1all    = (u16*)alloc(2097152ULL * 2);
  float* bias0    = (float*)alloc(1024ULL * 4);
  float* bias1    = (float*)alloc(1024ULL * 4);
  u32*   flags    = (u32*)alloc(16384ULL);
  if (off > ws_size) return;  // workspace too small -> visible failure

  float* outlog  = (float*)d_out;                 // [2048][31999]
  float* outattn = outlog + 65533952ULL;          // [32][64][128]

  (void)hipMemsetAsync(flags, 0, 16384, stream);

  prep_kernel<<<2048, 256, 0, stream>>>(
      fcw, enc, wenc, wdec, wih0, whh0, wih1, whh1,
      bih0, bhh0, bih1, bhh1, emb, yin, dih,
      fcwb, encb, wencb, wdecb, w0eh, w0ctx, w1cat, embbt, bias0, bias1,
      h0buf, h1buf);

  // enc_proj (prescaled, bf16): [4096][512] = encb @ wencb^T
  gemm128b<<<32 * 4, 256, 0, stream>>>(encb, wencb, encprojb, 1024, 512, 4);
  // encW0T (bf16): [1024 j][4096 bs] = w0ctx @ encb^T
  gemm128b<<<8 * 32, 256, 0, stream>>>(w0ctx, encb, encW0T, 1024, 4096, 32);

  (void)hipFuncSetAttribute((const void*)decoder_persistent,
                            hipFuncAttributeMaxDynamicSharedMemorySize, 157184);
  decoder_persistent<<<256, 512, 157184, stream>>>(
      wdecb, w0eh, w1cat, encprojb, encW0T, embbt, bias0, bias1,
      vw, msk, fcwb, fcb, partials, attbufB, h0buf, h1buf, h1all,
      outattn, outlog, flags);
}